// Round 2
// baseline (1500.265 us; speedup 1.0000x reference)
//
#include <hip/hip_runtime.h>

#define NP_ 1500000
#define NV_ 1200000
#define S_  50000
#define E_  1600000

// ---------------- CSR build ----------------

__global__ void k_zero2(int* a, int* b, int n) {
    int i = blockIdx.x * blockDim.x + threadIdx.x;
    if (i < n) { a[i] = 0; b[i] = 0; }
}

// single atomic pass: rank within segment + counts (counter doubles as histogram)
__global__ __launch_bounds__(256) void k_rank(
    const int* __restrict__ sp, int* __restrict__ pcnt,
    const int* __restrict__ eu, int* __restrict__ ecnt,
    int* __restrict__ rank)
{
    int i = blockIdx.x * 256 + threadIdx.x;
    if (i < NP_) {
        rank[i] = atomicAdd(&pcnt[sp[i]], 1);
    } else if (i < NP_ + E_) {
        rank[i] = atomicAdd(&ecnt[eu[i - NP_]], 1);
    }
}

// exclusive scan over S_ ints; block 0 -> points, block 1 -> edges
__global__ void k_scan2(const int* __restrict__ pcnt, int* __restrict__ pstart,
                        const int* __restrict__ ecnt, int* __restrict__ estart) {
    __shared__ int sums[1024];
    const int* cnt = (blockIdx.x == 0) ? pcnt : ecnt;
    int* start = (blockIdx.x == 0) ? pstart : estart;
    const int n = S_;
    int t = threadIdx.x;
    int chunk = (n + 1023) / 1024;
    int lo = t * chunk;
    int hi = lo + chunk; if (hi > n) hi = n;
    int s = 0;
    for (int i = lo; i < hi; i++) s += cnt[i];
    sums[t] = s;
    __syncthreads();
    for (int off = 1; off < 1024; off <<= 1) {
        int v = (t >= off) ? sums[t - off] : 0;
        __syncthreads();
        sums[t] += v;
        __syncthreads();
    }
    int run = sums[t] - s;  // exclusive prefix
    for (int i = lo; i < hi; i++) { start[i] = run; run += cnt[i]; }
    if (t == 1023) start[n] = run;
}

// atomic-free scatter: points fill vidx; edges fill list/evs + fused pos MLP
__global__ __launch_bounds__(256) void k_scatter(
    const int* __restrict__ sp, const int* __restrict__ imap,
    const int* __restrict__ pstart, int* __restrict__ vidx,
    const int* __restrict__ eu, const int* __restrict__ ev,
    const int* __restrict__ estart,
    int* __restrict__ elist, int* __restrict__ evsarr,
    const int* __restrict__ rank,
    const float* __restrict__ ctr,
    const float* __restrict__ pw1, const float* __restrict__ pb1,
    const float* __restrict__ pw2, const float* __restrict__ pb2,
    float* __restrict__ posv)
{
    int i = blockIdx.x * 256 + threadIdx.x;
    if (i < NP_) {
        vidx[pstart[sp[i]] + rank[i]] = imap[i];
    } else if (i < NP_ + E_) {
        int e = i - NP_;
        int u = eu[e], w = ev[e];
        int r = estart[u] + rank[i];
        elist[r] = e;
        evsarr[r] = w;
        float dx = ctr[u * 3]     - ctr[w * 3];
        float dy = ctr[u * 3 + 1] - ctr[w * 3 + 1];
        float dz = ctr[u * 3 + 2] - ctr[w * 3 + 2];
        float pos = pb2[0];   // uniform -> s_load
        #pragma unroll
        for (int hh = 0; hh < 16; hh++) {
            float aa = pb1[hh] + dx * pw1[hh * 3] + dy * pw1[hh * 3 + 1] + dz * pw1[hh * 3 + 2];
            pos += fmaxf(aa, 0.0f) * pw2[hh];
        }
        posv[r] = pos;
    }
}

// ---------------- point semantic head: gather + 32->32 BN ReLU ->20 ----------------
// one thread per point; weights wave-uniform -> s_load (scalar pipe overlaps VALU)

__global__ __launch_bounds__(256, 4) void k_point_head(
    const float* __restrict__ feats, const int* __restrict__ imap,
    const float* __restrict__ W1, const float* __restrict__ b1,
    const float* __restrict__ g, const float* __restrict__ be,
    const float* __restrict__ W2, const float* __restrict__ b2,
    float* __restrict__ out, int n)
{
    int p = blockIdx.x * 256 + threadIdx.x;
    if (p >= n) return;
    const float4* src = (const float4*)(feats + (size_t)imap[p] * 32);
    float x[32];
    #pragma unroll
    for (int i = 0; i < 8; i++) {
        float4 t = src[i];
        x[i * 4] = t.x; x[i * 4 + 1] = t.y; x[i * 4 + 2] = t.z; x[i * 4 + 3] = t.w;
    }
    float o[20];
    #pragma unroll
    for (int c = 0; c < 20; c++) o[c] = b2[c];
    #pragma unroll
    for (int j = 0; j < 32; j++) {
        float a = b1[j];
        #pragma unroll
        for (int i = 0; i < 32; i++) a = fmaf(x[i], W1[j * 32 + i], a);
        a = a * (g[j] * 0.9999500037f) + be[j];
        a = fmaxf(a, 0.0f);
        #pragma unroll
        for (int c = 0; c < 20; c++) o[c] = fmaf(a, W2[c * 32 + j], o[c]);
    }
    float4* dst = (float4*)(out + (size_t)p * 20);
    #pragma unroll
    for (int i = 0; i < 5; i++) {
        float4 o4;
        o4.x = o[i * 4]; o4.y = o[i * 4 + 1]; o4.z = o[i * 4 + 2]; o4.w = o[i * 4 + 3];
        dst[i] = o4;
    }
}

// ---------------- segment mean via CSR (half-wave = 32 dims per superpoint) ----------------

__global__ __launch_bounds__(256) void k_mean(
    const float* __restrict__ feats, const int* __restrict__ vidx,
    const int* __restrict__ start, float* __restrict__ emb)
{
    int t = blockIdx.x * 256 + threadIdx.x;
    int s = t >> 5, d = t & 31;
    if (s >= S_) return;
    int beg = start[s], end = start[s + 1];
    float acc = 0.0f;
    int i = beg;
    for (; i + 4 <= end; i += 4) {
        int p0 = vidx[i], p1 = vidx[i + 1], p2 = vidx[i + 2], p3 = vidx[i + 3];
        float f0 = feats[(size_t)p0 * 32 + d];
        float f1 = feats[(size_t)p1 * 32 + d];
        float f2 = feats[(size_t)p2 * 32 + d];
        float f3 = feats[(size_t)p3 * 32 + d];
        acc += f0 + f1 + f2 + f3;
    }
    for (; i < end; i++) acc += feats[(size_t)vidx[i] * 32 + d];
    float c = (float)(end - beg);
    emb[(size_t)s * 32 + d] = acc / fmaxf(c, 1.0f);
}

// ---------------- ecc = emb @ W_ecc.T : one thread per row, scalar weights ----------------

__global__ __launch_bounds__(64) void k_ecc(
    const float* __restrict__ emb, const float* __restrict__ Wecc, float* __restrict__ ecc)
{
    int s = blockIdx.x * 64 + threadIdx.x;
    if (s >= S_) return;
    float x[32];
    const float4* src = (const float4*)(emb + (size_t)s * 32);
    #pragma unroll
    for (int i = 0; i < 8; i++) {
        float4 t = src[i];
        x[i * 4] = t.x; x[i * 4 + 1] = t.y; x[i * 4 + 2] = t.z; x[i * 4 + 3] = t.w;
    }
    for (int j0 = 0; j0 < 64; j0 += 4) {
        float a[4] = {0.f, 0.f, 0.f, 0.f};
        #pragma unroll
        for (int u = 0; u < 4; u++)
            #pragma unroll
            for (int i = 0; i < 32; i++) a[u] = fmaf(x[i], Wecc[(j0 + u) * 32 + i], a[u]);
        float4 o4; o4.x = a[0]; o4.y = a[1]; o4.z = a[2]; o4.w = a[3];
        *(float4*)(ecc + (size_t)s * 64 + j0) = o4;
    }
}

// ---------------- q,k,v: one thread per row; kv interleaved [k(64)|v(64)] ----------------

__global__ __launch_bounds__(64) void k_qkv(
    const float* __restrict__ ecc,
    const float* __restrict__ Wq, const float* __restrict__ Wk, const float* __restrict__ Wv,
    float* __restrict__ q, float* __restrict__ kv)
{
    int s = blockIdx.x * 64 + threadIdx.x;
    if (s >= S_) return;
    float x[64];
    const float4* src = (const float4*)(ecc + (size_t)s * 64);
    #pragma unroll
    for (int i = 0; i < 16; i++) {
        float4 t = src[i];
        x[i * 4] = t.x; x[i * 4 + 1] = t.y; x[i * 4 + 2] = t.z; x[i * 4 + 3] = t.w;
    }
    for (int j0 = 0; j0 < 64; j0 += 4) {
        float aq[4] = {0.f, 0.f, 0.f, 0.f};
        float ak[4] = {0.f, 0.f, 0.f, 0.f};
        float av[4] = {0.f, 0.f, 0.f, 0.f};
        #pragma unroll
        for (int u = 0; u < 4; u++) {
            #pragma unroll
            for (int i = 0; i < 64; i++) {
                float xi = x[i];
                aq[u] = fmaf(xi, Wq[(j0 + u) * 64 + i], aq[u]);
                ak[u] = fmaf(xi, Wk[(j0 + u) * 64 + i], ak[u]);
                av[u] = fmaf(xi, Wv[(j0 + u) * 64 + i], av[u]);
            }
        }
        float4 t;
        t.x = aq[0]; t.y = aq[1]; t.z = aq[2]; t.w = aq[3];
        *(float4*)(q + (size_t)s * 64 + j0) = t;
        t.x = ak[0]; t.y = ak[1]; t.z = ak[2]; t.w = ak[3];
        *(float4*)(kv + (size_t)s * 128 + j0) = t;
        t.x = av[0]; t.y = av[1]; t.z = av[2]; t.w = av[3];
        *(float4*)(kv + (size_t)s * 128 + 64 + j0) = t;
    }
}

// ---------------- 4 fused ecc-heads (ssem/soff/socc/ssize), one thread per row ----------------

__global__ __launch_bounds__(64) void k_heads4(
    const float* __restrict__ ecc,
    const float* __restrict__ W1s, const float* __restrict__ b1s, const float* __restrict__ gs,
    const float* __restrict__ bes, const float* __restrict__ W2s, const float* __restrict__ b2s,
    const float* __restrict__ W1o, const float* __restrict__ b1o, const float* __restrict__ go,
    const float* __restrict__ beo, const float* __restrict__ W2o, const float* __restrict__ b2o,
    const float* __restrict__ W1c, const float* __restrict__ b1c, const float* __restrict__ gc,
    const float* __restrict__ bec, const float* __restrict__ W2c, const float* __restrict__ b2c,
    const float* __restrict__ W1z, const float* __restrict__ b1z, const float* __restrict__ gz,
    const float* __restrict__ bez, const float* __restrict__ W2z, const float* __restrict__ b2z,
    float* __restrict__ osem, float* __restrict__ ooff,
    float* __restrict__ oocc, float* __restrict__ osiz)
{
    int s = blockIdx.x * 64 + threadIdx.x;
    if (s >= S_) return;
    float x[64];
    const float4* src = (const float4*)(ecc + (size_t)s * 64);
    #pragma unroll
    for (int i = 0; i < 16; i++) {
        float4 t = src[i];
        x[i * 4] = t.x; x[i * 4 + 1] = t.y; x[i * 4 + 2] = t.z; x[i * 4 + 3] = t.w;
    }
    float as[20], ao[3], ac, az;
    #pragma unroll
    for (int c = 0; c < 20; c++) as[c] = b2s[c];
    #pragma unroll
    for (int c = 0; c < 3; c++) ao[c] = b2o[c];
    ac = b2c[0]; az = b2z[0];
    for (int j = 0; j < 64; j++) {
        float h0 = b1s[j], h1 = b1o[j], h2 = b1c[j], h3 = b1z[j];
        #pragma unroll
        for (int i = 0; i < 64; i++) {
            float xi = x[i];
            h0 = fmaf(xi, W1s[j * 64 + i], h0);
            h1 = fmaf(xi, W1o[j * 64 + i], h1);
            h2 = fmaf(xi, W1c[j * 64 + i], h2);
            h3 = fmaf(xi, W1z[j * 64 + i], h3);
        }
        h0 = fmaxf(h0 * (gs[j] * 0.9999500037f) + bes[j], 0.f);
        h1 = fmaxf(h1 * (go[j] * 0.9999500037f) + beo[j], 0.f);
        h2 = fmaxf(h2 * (gc[j] * 0.9999500037f) + bec[j], 0.f);
        h3 = fmaxf(h3 * (gz[j] * 0.9999500037f) + bez[j], 0.f);
        #pragma unroll
        for (int c = 0; c < 20; c++) as[c] = fmaf(h0, W2s[c * 64 + j], as[c]);
        #pragma unroll
        for (int c = 0; c < 3; c++) ao[c] = fmaf(h1, W2o[c * 64 + j], ao[c]);
        ac = fmaf(h2, W2c[j], ac);
        az = fmaf(h3, W2z[j], az);
    }
    float4* d = (float4*)(osem + (size_t)s * 20);
    #pragma unroll
    for (int i = 0; i < 5; i++) {
        float4 o4;
        o4.x = as[i * 4]; o4.y = as[i * 4 + 1]; o4.z = as[i * 4 + 2]; o4.w = as[i * 4 + 3];
        d[i] = o4;
    }
    ooff[(size_t)s * 3]     = ao[0];
    ooff[(size_t)s * 3 + 1] = ao[1];
    ooff[(size_t)s * 3 + 2] = ao[2];
    oocc[s] = ac;
    osiz[s] = az;
}

// ---------------- disc head (featb -> 7), one thread per row ----------------

__global__ __launch_bounds__(64) void k_featd(
    const float* __restrict__ in,
    const float* __restrict__ W1, const float* __restrict__ b1,
    const float* __restrict__ g, const float* __restrict__ be,
    const float* __restrict__ W2, const float* __restrict__ b2,
    float* __restrict__ out)
{
    int s = blockIdx.x * 64 + threadIdx.x;
    if (s >= S_) return;
    float x[64];
    const float4* src = (const float4*)(in + (size_t)s * 64);
    #pragma unroll
    for (int i = 0; i < 16; i++) {
        float4 t = src[i];
        x[i * 4] = t.x; x[i * 4 + 1] = t.y; x[i * 4 + 2] = t.z; x[i * 4 + 3] = t.w;
    }
    float o[7];
    #pragma unroll
    for (int c = 0; c < 7; c++) o[c] = b2[c];
    for (int j = 0; j < 64; j++) {
        float a = b1[j];
        #pragma unroll
        for (int i = 0; i < 64; i++) a = fmaf(x[i], W1[j * 64 + i], a);
        a = fmaxf(a * (g[j] * 0.9999500037f) + be[j], 0.f);
        #pragma unroll
        for (int c = 0; c < 7; c++) o[c] = fmaf(a, W2[c * 64 + j], o[c]);
    }
    #pragma unroll
    for (int c = 0; c < 7; c++) out[(size_t)s * 7 + c] = o[c];
}

// ---------------- fused attention: single gather sweep, online softmax ----------------

__global__ __launch_bounds__(256) void k_attn(
    const int* __restrict__ start, const int* __restrict__ list,
    const int* __restrict__ evs, const float* __restrict__ posv,
    const float* __restrict__ q, const float* __restrict__ kv,
    const float* __restrict__ ecc,
    float* __restrict__ affs, float* __restrict__ soft, float* __restrict__ featb)
{
    int t = blockIdx.x * 256 + threadIdx.x;
    int s0 = t >> 6, lane = t & 63;
    if (s0 >= S_) return;
    int s = __builtin_amdgcn_readfirstlane(s0);  // uniform: evs/posv/affs scalarize
    int beg = start[s], end = start[s + 1];
    float qv = q[(size_t)s * 64 + lane];

    float m = -3.0e38f, tot = 0.0f, res = 0.0f;
    int r = beg;
    for (; r + 8 <= end; r += 8) {
        int e[8];
        #pragma unroll
        for (int u = 0; u < 8; u++) e[u] = evs[r + u];
        float kk[8], vv[8];
        #pragma unroll
        for (int u = 0; u < 8; u++) {
            const float* row = kv + (size_t)e[u] * 128;
            kk[u] = row[lane];
            vv[u] = row[64 + lane];
        }
        float p[8];
        #pragma unroll
        for (int u = 0; u < 8; u++) p[u] = qv * kk[u];
        #pragma unroll
        for (int o = 32; o; o >>= 1) {
            #pragma unroll
            for (int u = 0; u < 8; u++) p[u] += __shfl_xor(p[u], o, 64);
        }
        float a[8];
        float cm = -3.0e38f;
        #pragma unroll
        for (int u = 0; u < 8; u++) { a[u] = p[u] * 0.125f * posv[r + u]; cm = fmaxf(cm, a[u]); }
        float mn = fmaxf(m, cm);
        float scale = __expf(m - mn);
        res *= scale; tot *= scale; m = mn;
        #pragma unroll
        for (int u = 0; u < 8; u++) {
            float w = __expf(a[u] - m);
            tot += w;
            res = fmaf(w, vv[u], res);
        }
        float av = a[0];
        #pragma unroll
        for (int u = 1; u < 8; u++) av = (lane == u) ? a[u] : av;
        if (lane < 8) affs[r + lane] = av;
    }
    for (; r < end; r++) {
        const float* row = kv + (size_t)evs[r] * 128;
        float kk = row[lane], vv = row[64 + lane];
        float p = qv * kk;
        #pragma unroll
        for (int o = 32; o; o >>= 1) p += __shfl_xor(p, o, 64);
        float a = p * 0.125f * posv[r];
        float mn = fmaxf(m, a);
        float scale = __expf(m - mn);
        res *= scale; tot *= scale; m = mn;
        float w = __expf(a - m);
        tot += w;
        res = fmaf(w, vv, res);
        if (lane == 0) affs[r] = a;
    }
    float inv = tot > 0.0f ? 1.0f / tot : 0.0f;

    // soft scatter from coalesced affs re-read
    for (int i = beg + lane; i < end; i += 64) soft[list[i]] = __expf(affs[i] - m) * inv;

    featb[(size_t)s * 64 + lane] = ecc[(size_t)s * 64 + lane] + res * inv;
}

// ---------------- launch ----------------

extern "C" void kernel_launch(void* const* d_in, const int* in_sizes, int n_in,
                              void* d_out, int out_size, void* d_ws, size_t ws_size,
                              hipStream_t stream) {
    const float* output_feats = (const float*)d_in[0];
    const int*   input_map    = (const int*)d_in[1];
    const int*   superpoint   = (const int*)d_in[2];
    const float* ctr          = (const float*)d_in[3];
    const int*   edge_u       = (const int*)d_in[4];
    const int*   edge_v       = (const int*)d_in[5];
    const float* W_ecc        = (const float*)d_in[6];
    const float* lin_W1 = (const float*)d_in[7];
    const float* lin_b1 = (const float*)d_in[8];
    const float* lin_g  = (const float*)d_in[9];
    const float* lin_be = (const float*)d_in[10];
    const float* lin_W2 = (const float*)d_in[11];
    const float* lin_b2 = (const float*)d_in[12];
    const float* pos_W1 = (const float*)d_in[43];
    const float* pos_b1 = (const float*)d_in[44];
    const float* pos_W2 = (const float*)d_in[45];
    const float* pos_b2 = (const float*)d_in[46];
    const float* Wq     = (const float*)d_in[47];
    const float* Wk     = (const float*)d_in[48];
    const float* Wv     = (const float*)d_in[49];

    float* out = (float*)d_out;
    float* o_sem    = out;                    // [NP,20]
    float* o_spsem  = out + 30000000;         // [S,20]
    float* o_spoff  = out + 31000000;         // [S,3]
    float* o_spocc  = out + 31150000;         // [S]
    float* o_spsize = out + 31200000;         // [S]
    float* o_soft   = out + 31250000;         // [E]
    float* o_spdisc = out + 32850000;         // [S,7]

    // workspace layout
    char* base = (char*)d_ws;
    size_t off = 0;
    auto alloc = [&](size_t bytes) -> char* {
        char* p = base + off;
        off = (off + bytes + 255) & ~(size_t)255;
        return p;
    };
    int*   pt_cnt   = (int*)alloc(S_ * 4);
    int*   pt_start = (int*)alloc((S_ + 1) * 4);
    int*   e_cnt    = (int*)alloc(S_ * 4);
    int*   e_start  = (int*)alloc((S_ + 1) * 4);
    int*   vidx     = (int*)alloc((size_t)NP_ * 4);
    int*   e_list   = (int*)alloc((size_t)E_ * 4);
    int*   e_vs     = (int*)alloc((size_t)E_ * 4);
    float* affs     = (float*)alloc((size_t)E_ * 4);
    float* posv     = (float*)alloc((size_t)E_ * 4);
    float* emb      = (float*)alloc((size_t)S_ * 32 * 4);   // 6.4 MB (multiple of 256)
    float* ecc      = (float*)alloc((size_t)S_ * 64 * 4);   // contiguous after emb
    float* qb       = (float*)alloc((size_t)S_ * 64 * 4);
    float* kvb      = (float*)alloc((size_t)S_ * 128 * 4);
    float* featb    = qb;            // overlay: wave s reads q-row s before writing featb-row s
    int*   rank     = (int*)emb;     // overlay: rank dead before k_mean writes emb
                                     // (NP_+E_)*4 = 12.4 MB < emb(6.4) + ecc(12.8)

    const int NTOT = NP_ + E_;

    k_zero2<<<(S_ + 255) / 256, 256, 0, stream>>>(pt_cnt, e_cnt, S_);
    k_rank<<<(NTOT + 255) / 256, 256, 0, stream>>>(superpoint, pt_cnt, edge_u, e_cnt, rank);
    k_scan2<<<2, 1024, 0, stream>>>(pt_cnt, pt_start, e_cnt, e_start);
    k_scatter<<<(NTOT + 255) / 256, 256, 0, stream>>>(
        superpoint, input_map, pt_start, vidx,
        edge_u, edge_v, e_start, e_list, e_vs, rank,
        ctr, pos_W1, pos_b1, pos_W2, pos_b2, posv);
    k_point_head<<<(NP_ + 255) / 256, 256, 0, stream>>>(
        output_feats, input_map, lin_W1, lin_b1, lin_g, lin_be, lin_W2, lin_b2, o_sem, NP_);
    k_mean<<<(S_ * 32) / 256, 256, 0, stream>>>(output_feats, vidx, pt_start, emb);
    k_ecc<<<(S_ + 63) / 64, 64, 0, stream>>>(emb, W_ecc, ecc);
    k_qkv<<<(S_ + 63) / 64, 64, 0, stream>>>(ecc, Wq, Wk, Wv, qb, kvb);
    k_heads4<<<(S_ + 63) / 64, 64, 0, stream>>>(ecc,
        (const float*)d_in[13], (const float*)d_in[14], (const float*)d_in[15],
        (const float*)d_in[16], (const float*)d_in[17], (const float*)d_in[18],
        (const float*)d_in[19], (const float*)d_in[20], (const float*)d_in[21],
        (const float*)d_in[22], (const float*)d_in[23], (const float*)d_in[24],
        (const float*)d_in[25], (const float*)d_in[26], (const float*)d_in[27],
        (const float*)d_in[28], (const float*)d_in[29], (const float*)d_in[30],
        (const float*)d_in[31], (const float*)d_in[32], (const float*)d_in[33],
        (const float*)d_in[34], (const float*)d_in[35], (const float*)d_in[36],
        o_spsem, o_spoff, o_spocc, o_spsize);
    k_attn<<<S_ / 4, 256, 0, stream>>>(e_start, e_list, e_vs, posv, qb, kvb, ecc,
        affs, o_soft, featb);
    k_featd<<<(S_ + 63) / 64, 64, 0, stream>>>(featb,
        (const float*)d_in[37], (const float*)d_in[38], (const float*)d_in[39],
        (const float*)d_in[40], (const float*)d_in[41], (const float*)d_in[42],
        o_spdisc);
}

// Round 3
// 1164.112 us; speedup vs baseline: 1.2888x; 1.2888x over previous
//
#include <hip/hip_runtime.h>

#define NP_ 1500000
#define NV_ 1200000
#define S_  50000
#define E_  1600000

// ---------------- helpers ----------------

__device__ __forceinline__ float dot64u(const float4* __restrict__ xr, const float4* w) {
    float h0 = 0.f, h1 = 0.f, h2 = 0.f, h3 = 0.f;
    #pragma unroll
    for (int c = 0; c < 16; c++) {
        float4 xa = xr[c];   // wave-uniform
        float4 wa = w[c];    // per-lane, in VGPRs
        h0 = fmaf(xa.x, wa.x, h0);
        h1 = fmaf(xa.y, wa.y, h1);
        h2 = fmaf(xa.z, wa.z, h2);
        h3 = fmaf(xa.w, wa.w, h3);
    }
    return (h0 + h1) + (h2 + h3);
}

__device__ __forceinline__ float dot32u(const float4* __restrict__ xr, const float4* w) {
    float h0 = 0.f, h1 = 0.f, h2 = 0.f, h3 = 0.f;
    #pragma unroll
    for (int c = 0; c < 8; c++) {
        float4 xa = xr[c];
        float4 wa = w[c];
        h0 = fmaf(xa.x, wa.x, h0);
        h1 = fmaf(xa.y, wa.y, h1);
        h2 = fmaf(xa.z, wa.z, h2);
        h3 = fmaf(xa.w, wa.w, h3);
    }
    return (h0 + h1) + (h2 + h3);
}

__device__ __forceinline__ float wred(float p) {
    #pragma unroll
    for (int o = 32; o; o >>= 1) p += __shfl_xor(p, o, 64);
    return p;
}

// ---------------- CSR build ----------------

__global__ void k_zero2(int* a, int* b, int n) {
    int i = blockIdx.x * blockDim.x + threadIdx.x;
    if (i < n) { a[i] = 0; b[i] = 0; }
}

// single atomic pass: rank within segment + counts (counter doubles as histogram)
__global__ __launch_bounds__(256) void k_rank(
    const int* __restrict__ sp, int* __restrict__ pcnt,
    const int* __restrict__ eu, int* __restrict__ ecnt,
    int* __restrict__ rank)
{
    int i = blockIdx.x * 256 + threadIdx.x;
    if (i < NP_) {
        rank[i] = atomicAdd(&pcnt[sp[i]], 1);
    } else if (i < NP_ + E_) {
        rank[i] = atomicAdd(&ecnt[eu[i - NP_]], 1);
    }
}

// exclusive scan over S_ ints; block 0 -> points, block 1 -> edges
__global__ void k_scan2(const int* __restrict__ pcnt, int* __restrict__ pstart,
                        const int* __restrict__ ecnt, int* __restrict__ estart) {
    __shared__ int sums[1024];
    const int* cnt = (blockIdx.x == 0) ? pcnt : ecnt;
    int* start = (blockIdx.x == 0) ? pstart : estart;
    const int n = S_;
    int t = threadIdx.x;
    int chunk = (n + 1023) / 1024;
    int lo = t * chunk;
    int hi = lo + chunk; if (hi > n) hi = n;
    int s = 0;
    for (int i = lo; i < hi; i++) s += cnt[i];
    sums[t] = s;
    __syncthreads();
    for (int off = 1; off < 1024; off <<= 1) {
        int v = (t >= off) ? sums[t - off] : 0;
        __syncthreads();
        sums[t] += v;
        __syncthreads();
    }
    int run = sums[t] - s;  // exclusive prefix
    for (int i = lo; i < hi; i++) { start[i] = run; run += cnt[i]; }
    if (t == 1023) start[n] = run;
}

// atomic-free scatter: points fill vidx; edges fill list/evs + fused pos MLP
__global__ __launch_bounds__(256) void k_scatter(
    const int* __restrict__ sp, const int* __restrict__ imap,
    const int* __restrict__ pstart, int* __restrict__ vidx,
    const int* __restrict__ eu, const int* __restrict__ ev,
    const int* __restrict__ estart,
    int* __restrict__ elist, int* __restrict__ evsarr,
    const int* __restrict__ rank,
    const float* __restrict__ ctr,
    const float* __restrict__ pw1, const float* __restrict__ pb1,
    const float* __restrict__ pw2, const float* __restrict__ pb2,
    float* __restrict__ posv)
{
    int i = blockIdx.x * 256 + threadIdx.x;
    if (i < NP_) {
        vidx[pstart[sp[i]] + rank[i]] = imap[i];
    } else if (i < NP_ + E_) {
        int e = i - NP_;
        int u = eu[e], w = ev[e];
        int r = estart[u] + rank[i];
        elist[r] = e;
        evsarr[r] = w;
        float dx = ctr[u * 3]     - ctr[w * 3];
        float dy = ctr[u * 3 + 1] - ctr[w * 3 + 1];
        float dz = ctr[u * 3 + 2] - ctr[w * 3 + 2];
        float pos = pb2[0];   // uniform -> s_load
        #pragma unroll
        for (int hh = 0; hh < 16; hh++) {
            float aa = pb1[hh] + dx * pw1[hh * 3] + dy * pw1[hh * 3 + 1] + dz * pw1[hh * 3 + 2];
            pos += fmaxf(aa, 0.0f) * pw2[hh];
        }
        posv[r] = pos;
    }
}

// ---------------- point semantic head: gather + 32->32 BN ReLU ->20 ----------------
// one thread per point (1.5M threads -> occupancy-rich); weights wave-uniform -> scalar
// cache (6.5 KB fits scalar L1, stays hot per CU)

__global__ __launch_bounds__(256, 4) void k_point_head(
    const float* __restrict__ feats, const int* __restrict__ imap,
    const float* __restrict__ W1, const float* __restrict__ b1,
    const float* __restrict__ g, const float* __restrict__ be,
    const float* __restrict__ W2, const float* __restrict__ b2,
    float* __restrict__ out, int n)
{
    int p = blockIdx.x * 256 + threadIdx.x;
    if (p >= n) return;
    const float4* src = (const float4*)(feats + (size_t)imap[p] * 32);
    float x[32];
    #pragma unroll
    for (int i = 0; i < 8; i++) {
        float4 t = src[i];
        x[i * 4] = t.x; x[i * 4 + 1] = t.y; x[i * 4 + 2] = t.z; x[i * 4 + 3] = t.w;
    }
    float o[20];
    #pragma unroll
    for (int c = 0; c < 20; c++) o[c] = b2[c];
    #pragma unroll
    for (int j = 0; j < 32; j++) {
        float a = b1[j];
        #pragma unroll
        for (int i = 0; i < 32; i++) a = fmaf(x[i], W1[j * 32 + i], a);
        a = a * (g[j] * 0.9999500037f) + be[j];
        a = fmaxf(a, 0.0f);
        #pragma unroll
        for (int c = 0; c < 20; c++) o[c] = fmaf(a, W2[c * 32 + j], o[c]);
    }
    float4* dst = (float4*)(out + (size_t)p * 20);
    #pragma unroll
    for (int i = 0; i < 5; i++) {
        float4 o4;
        o4.x = o[i * 4]; o4.y = o[i * 4 + 1]; o4.z = o[i * 4 + 2]; o4.w = o[i * 4 + 3];
        dst[i] = o4;
    }
}

// ---------------- segment mean via CSR (half-wave = 32 dims per superpoint) ----------------

__global__ __launch_bounds__(256) void k_mean(
    const float* __restrict__ feats, const int* __restrict__ vidx,
    const int* __restrict__ start, float* __restrict__ emb)
{
    int t = blockIdx.x * 256 + threadIdx.x;
    int s = t >> 5, d = t & 31;
    if (s >= S_) return;
    int beg = start[s], end = start[s + 1];
    float acc = 0.0f;
    int i = beg;
    for (; i + 4 <= end; i += 4) {
        int p0 = vidx[i], p1 = vidx[i + 1], p2 = vidx[i + 2], p3 = vidx[i + 3];
        float f0 = feats[(size_t)p0 * 32 + d];
        float f1 = feats[(size_t)p1 * 32 + d];
        float f2 = feats[(size_t)p2 * 32 + d];
        float f3 = feats[(size_t)p3 * 32 + d];
        acc += f0 + f1 + f2 + f3;
    }
    for (; i < end; i++) acc += feats[(size_t)vidx[i] * 32 + d];
    float c = (float)(end - beg);
    emb[(size_t)s * 32 + d] = acc / fmaxf(c, 1.0f);
}

// ---------------- ecc: wave-per-row, W row resident in VGPRs ----------------

__global__ __launch_bounds__(256) void k_ecc(
    const float* __restrict__ emb, const float* __restrict__ Wecc, float* __restrict__ ecc)
{
    int wid = threadIdx.x >> 6, lane = threadIdx.x & 63;
    float4 w[8];
    const float4* Wp = (const float4*)(Wecc + (size_t)lane * 32);
    #pragma unroll
    for (int i = 0; i < 8; i++) w[i] = Wp[i];
    for (int r = blockIdx.x * 4 + wid; r < S_; r += gridDim.x * 4) {
        float a = dot32u((const float4*)(emb + (size_t)r * 32), w);
        ecc[(size_t)r * 64 + lane] = a;
    }
}

// ---------------- fused superpoint matmuls: 7 role waves ----------------
// w0=q  w1=k  w2=v  w3=ssem  w4=soff  w5=socc  w6=ssize
// All waves stream the same ecc rows (scalar-cache sharing); weights in VGPRs; no barriers.

__global__ __launch_bounds__(448) void k_super(
    const float* __restrict__ ecc,
    const float* __restrict__ Wq, const float* __restrict__ Wk, const float* __restrict__ Wv,
    const float* __restrict__ W1s, const float* __restrict__ b1s, const float* __restrict__ gs,
    const float* __restrict__ bes, const float* __restrict__ W2s, const float* __restrict__ b2s,
    const float* __restrict__ W1o, const float* __restrict__ b1o, const float* __restrict__ go,
    const float* __restrict__ beo, const float* __restrict__ W2o, const float* __restrict__ b2o,
    const float* __restrict__ W1c, const float* __restrict__ b1c, const float* __restrict__ gc,
    const float* __restrict__ bec, const float* __restrict__ W2c, const float* __restrict__ b2c,
    const float* __restrict__ W1z, const float* __restrict__ b1z, const float* __restrict__ gz,
    const float* __restrict__ bez, const float* __restrict__ W2z, const float* __restrict__ b2z,
    float* __restrict__ q, float* __restrict__ kv,
    float* __restrict__ osem, float* __restrict__ ooff,
    float* __restrict__ oocc, float* __restrict__ osiz)
{
    int wid = threadIdx.x >> 6, lane = threadIdx.x & 63;
    __shared__ float hb[68];   // wave 3 private

    if (wid < 3) {
        // pure 64x64 linear
        const float* W = (wid == 0) ? Wq : (wid == 1) ? Wk : Wv;
        float* outp; size_t stride;
        if (wid == 0)      { outp = q;       stride = 64;  }
        else if (wid == 1) { outp = kv;      stride = 128; }
        else               { outp = kv + 64; stride = 128; }
        float4 w[16];
        const float4* Wp = (const float4*)(W + (size_t)lane * 64);
        #pragma unroll
        for (int i = 0; i < 16; i++) w[i] = Wp[i];
        for (int r = blockIdx.x; r < S_; r += gridDim.x) {
            float a = dot64u((const float4*)(ecc + (size_t)r * 64), w);
            outp[(size_t)r * stride + lane] = a;
        }
    } else if (wid == 3) {
        // ssem: 64 -> 64 BN ReLU -> 20 (layer2 via LDS broadcast of h)
        float4 w1[16], w2[16];
        { const float4* p = (const float4*)(W1s + (size_t)lane * 64);
          #pragma unroll
          for (int i = 0; i < 16; i++) w1[i] = p[i]; }
        { int r2 = lane < 20 ? lane : 19;
          const float4* p = (const float4*)(W2s + (size_t)r2 * 64);
          #pragma unroll
          for (int i = 0; i < 16; i++) w2[i] = p[i]; }
        float b1v = b1s[lane], sc = gs[lane] * 0.9999500037f, bev = bes[lane];
        float b2v = lane < 20 ? b2s[lane] : 0.f;
        for (int r = blockIdx.x; r < S_; r += gridDim.x) {
            float h = dot64u((const float4*)(ecc + (size_t)r * 64), w1) + b1v;
            h = fmaxf(h * sc + bev, 0.f);
            hb[lane] = h;
            float a0 = b2v, a1 = 0.f, a2 = 0.f, a3 = 0.f;
            const float4* hb4 = (const float4*)hb;
            #pragma unroll
            for (int c = 0; c < 16; c++) {
                float4 hh = hb4[c];    // broadcast (uniform addr)
                float4 ww = w2[c];
                a0 = fmaf(hh.x, ww.x, a0); a1 = fmaf(hh.y, ww.y, a1);
                a2 = fmaf(hh.z, ww.z, a2); a3 = fmaf(hh.w, ww.w, a3);
            }
            if (lane < 20) osem[(size_t)r * 20 + lane] = (a0 + a1) + (a2 + a3);
        }
    } else if (wid == 4) {
        // soff: 64 -> 64 BN ReLU -> 3 (shuffle reduce)
        float4 w1[16];
        { const float4* p = (const float4*)(W1o + (size_t)lane * 64);
          #pragma unroll
          for (int i = 0; i < 16; i++) w1[i] = p[i]; }
        float w20 = W2o[lane], w21 = W2o[64 + lane], w22 = W2o[128 + lane];
        float b1v = b1o[lane], sc = go[lane] * 0.9999500037f, bev = beo[lane];
        float b20 = b2o[0], b21 = b2o[1], b22 = b2o[2];
        for (int r = blockIdx.x; r < S_; r += gridDim.x) {
            float h = dot64u((const float4*)(ecc + (size_t)r * 64), w1) + b1v;
            h = fmaxf(h * sc + bev, 0.f);
            float p0 = h * w20, p1 = h * w21, p2 = h * w22;
            #pragma unroll
            for (int o = 32; o; o >>= 1) {
                p0 += __shfl_xor(p0, o, 64);
                p1 += __shfl_xor(p1, o, 64);
                p2 += __shfl_xor(p2, o, 64);
            }
            if (lane == 0) {
                ooff[(size_t)r * 3]     = p0 + b20;
                ooff[(size_t)r * 3 + 1] = p1 + b21;
                ooff[(size_t)r * 3 + 2] = p2 + b22;
            }
        }
    } else {
        // wid 5: socc, wid 6: ssize  (64 -> 64 BN ReLU -> 1)
        const float* W1p = (wid == 5) ? W1c : W1z;
        const float* b1p = (wid == 5) ? b1c : b1z;
        const float* gp  = (wid == 5) ? gc  : gz;
        const float* bep = (wid == 5) ? bec : bez;
        const float* W2p = (wid == 5) ? W2c : W2z;
        const float* b2p = (wid == 5) ? b2c : b2z;
        float* outp = (wid == 5) ? oocc : osiz;
        float4 w1[16];
        { const float4* p = (const float4*)(W1p + (size_t)lane * 64);
          #pragma unroll
          for (int i = 0; i < 16; i++) w1[i] = p[i]; }
        float w2v = W2p[lane];
        float b1v = b1p[lane], sc = gp[lane] * 0.9999500037f, bev = bep[lane];
        float b20 = b2p[0];
        for (int r = blockIdx.x; r < S_; r += gridDim.x) {
            float h = dot64u((const float4*)(ecc + (size_t)r * 64), w1) + b1v;
            h = fmaxf(h * sc + bev, 0.f);
            float p = wred(h * w2v);
            if (lane == 0) outp[r] = p + b20;
        }
    }
}

// ---------------- disc head (featb -> 7): wave-per-row, weights in VGPRs ----------------

__global__ __launch_bounds__(256) void k_featd(
    const float* __restrict__ in,
    const float* __restrict__ W1, const float* __restrict__ b1,
    const float* __restrict__ g, const float* __restrict__ be,
    const float* __restrict__ W2, const float* __restrict__ b2,
    float* __restrict__ out)
{
    int wid = threadIdx.x >> 6, lane = threadIdx.x & 63;
    __shared__ float hb[4][68];
    float4 w1[16], w2[16];
    { const float4* p = (const float4*)(W1 + (size_t)lane * 64);
      #pragma unroll
      for (int i = 0; i < 16; i++) w1[i] = p[i]; }
    { int r2 = lane < 7 ? lane : 6;
      const float4* p = (const float4*)(W2 + (size_t)r2 * 64);
      #pragma unroll
      for (int i = 0; i < 16; i++) w2[i] = p[i]; }
    float b1v = b1[lane], sc = g[lane] * 0.9999500037f, bev = be[lane];
    float b2v = lane < 7 ? b2[lane] : 0.f;
    for (int r = blockIdx.x * 4 + wid; r < S_; r += gridDim.x * 4) {
        float h = dot64u((const float4*)(in + (size_t)r * 64), w1) + b1v;
        h = fmaxf(h * sc + bev, 0.f);
        hb[wid][lane] = h;
        float a0 = b2v, a1 = 0.f, a2 = 0.f, a3 = 0.f;
        const float4* hb4 = (const float4*)hb[wid];
        #pragma unroll
        for (int c = 0; c < 16; c++) {
            float4 hh = hb4[c];
            float4 ww = w2[c];
            a0 = fmaf(hh.x, ww.x, a0); a1 = fmaf(hh.y, ww.y, a1);
            a2 = fmaf(hh.z, ww.z, a2); a3 = fmaf(hh.w, ww.w, a3);
        }
        if (lane < 7) out[(size_t)r * 7 + lane] = (a0 + a1) + (a2 + a3);
    }
}

// ---------------- fused attention: single gather sweep, online softmax ----------------

__global__ __launch_bounds__(256) void k_attn(
    const int* __restrict__ start, const int* __restrict__ list,
    const int* __restrict__ evs, const float* __restrict__ posv,
    const float* __restrict__ q, const float* __restrict__ kv,
    const float* __restrict__ ecc,
    float* __restrict__ affs, float* __restrict__ soft, float* __restrict__ featb)
{
    int t = blockIdx.x * 256 + threadIdx.x;
    int s0 = t >> 6, lane = t & 63;
    if (s0 >= S_) return;
    int s = __builtin_amdgcn_readfirstlane(s0);  // uniform: evs/posv/affs scalarize
    int beg = start[s], end = start[s + 1];
    float qv = q[(size_t)s * 64 + lane];

    float m = -3.0e38f, tot = 0.0f, res = 0.0f;
    int r = beg;
    for (; r + 8 <= end; r += 8) {
        int e[8];
        #pragma unroll
        for (int u = 0; u < 8; u++) e[u] = evs[r + u];
        float kk[8], vv[8];
        #pragma unroll
        for (int u = 0; u < 8; u++) {
            const float* row = kv + (size_t)e[u] * 128;
            kk[u] = row[lane];
            vv[u] = row[64 + lane];
        }
        float p[8];
        #pragma unroll
        for (int u = 0; u < 8; u++) p[u] = qv * kk[u];
        #pragma unroll
        for (int o = 32; o; o >>= 1) {
            #pragma unroll
            for (int u = 0; u < 8; u++) p[u] += __shfl_xor(p[u], o, 64);
        }
        float a[8];
        float cm = -3.0e38f;
        #pragma unroll
        for (int u = 0; u < 8; u++) { a[u] = p[u] * 0.125f * posv[r + u]; cm = fmaxf(cm, a[u]); }
        float mn = fmaxf(m, cm);
        float scale = __expf(m - mn);
        res *= scale; tot *= scale; m = mn;
        #pragma unroll
        for (int u = 0; u < 8; u++) {
            float w = __expf(a[u] - m);
            tot += w;
            res = fmaf(w, vv[u], res);
        }
        float av = a[0];
        #pragma unroll
        for (int u = 1; u < 8; u++) av = (lane == u) ? a[u] : av;
        if (lane < 8) affs[r + lane] = av;
    }
    for (; r < end; r++) {
        const float* row = kv + (size_t)evs[r] * 128;
        float kk = row[lane], vv = row[64 + lane];
        float p = qv * kk;
        #pragma unroll
        for (int o = 32; o; o >>= 1) p += __shfl_xor(p, o, 64);
        float a = p * 0.125f * posv[r];
        float mn = fmaxf(m, a);
        float scale = __expf(m - mn);
        res *= scale; tot *= scale; m = mn;
        float w = __expf(a - m);
        tot += w;
        res = fmaf(w, vv, res);
        if (lane == 0) affs[r] = a;
    }
    float inv = tot > 0.0f ? 1.0f / tot : 0.0f;

    // soft scatter from coalesced affs re-read
    for (int i = beg + lane; i < end; i += 64) soft[list[i]] = __expf(affs[i] - m) * inv;

    featb[(size_t)s * 64 + lane] = ecc[(size_t)s * 64 + lane] + res * inv;
}

// ---------------- launch ----------------

extern "C" void kernel_launch(void* const* d_in, const int* in_sizes, int n_in,
                              void* d_out, int out_size, void* d_ws, size_t ws_size,
                              hipStream_t stream) {
    const float* output_feats = (const float*)d_in[0];
    const int*   input_map    = (const int*)d_in[1];
    const int*   superpoint   = (const int*)d_in[2];
    const float* ctr          = (const float*)d_in[3];
    const int*   edge_u       = (const int*)d_in[4];
    const int*   edge_v       = (const int*)d_in[5];
    const float* W_ecc        = (const float*)d_in[6];
    const float* lin_W1 = (const float*)d_in[7];
    const float* lin_b1 = (const float*)d_in[8];
    const float* lin_g  = (const float*)d_in[9];
    const float* lin_be = (const float*)d_in[10];
    const float* lin_W2 = (const float*)d_in[11];
    const float* lin_b2 = (const float*)d_in[12];
    const float* pos_W1 = (const float*)d_in[43];
    const float* pos_b1 = (const float*)d_in[44];
    const float* pos_W2 = (const float*)d_in[45];
    const float* pos_b2 = (const float*)d_in[46];
    const float* Wq     = (const float*)d_in[47];
    const float* Wk     = (const float*)d_in[48];
    const float* Wv     = (const float*)d_in[49];

    float* out = (float*)d_out;
    float* o_sem    = out;                    // [NP,20]
    float* o_spsem  = out + 30000000;         // [S,20]
    float* o_spoff  = out + 31000000;         // [S,3]
    float* o_spocc  = out + 31150000;         // [S]
    float* o_spsize = out + 31200000;         // [S]
    float* o_soft   = out + 31250000;         // [E]
    float* o_spdisc = out + 32850000;         // [S,7]

    // workspace layout
    char* base = (char*)d_ws;
    size_t off = 0;
    auto alloc = [&](size_t bytes) -> char* {
        char* p = base + off;
        off = (off + bytes + 255) & ~(size_t)255;
        return p;
    };
    int*   pt_cnt   = (int*)alloc(S_ * 4);
    int*   pt_start = (int*)alloc((S_ + 1) * 4);
    int*   e_cnt    = (int*)alloc(S_ * 4);
    int*   e_start  = (int*)alloc((S_ + 1) * 4);
    int*   vidx     = (int*)alloc((size_t)NP_ * 4);
    int*   e_list   = (int*)alloc((size_t)E_ * 4);
    int*   e_vs     = (int*)alloc((size_t)E_ * 4);
    float* affs     = (float*)alloc((size_t)E_ * 4);
    float* posv     = (float*)alloc((size_t)E_ * 4);
    float* emb      = (float*)alloc((size_t)S_ * 32 * 4);
    float* ecc      = (float*)alloc((size_t)S_ * 64 * 4);
    float* qb       = (float*)alloc((size_t)S_ * 64 * 4);
    float* kvb      = (float*)alloc((size_t)S_ * 128 * 4);
    float* featb    = qb;            // overlay: wave s reads q-row s before writing featb-row s
    int*   rank     = (int*)emb;     // overlay: rank dead before k_mean writes emb
                                     // (NP_+E_)*4 = 12.4 MB < emb(6.4) + ecc(12.8)

    const int NTOT = NP_ + E_;

    k_zero2<<<(S_ + 255) / 256, 256, 0, stream>>>(pt_cnt, e_cnt, S_);
    k_rank<<<(NTOT + 255) / 256, 256, 0, stream>>>(superpoint, pt_cnt, edge_u, e_cnt, rank);
    k_scan2<<<2, 1024, 0, stream>>>(pt_cnt, pt_start, e_cnt, e_start);
    k_scatter<<<(NTOT + 255) / 256, 256, 0, stream>>>(
        superpoint, input_map, pt_start, vidx,
        edge_u, edge_v, e_start, e_list, e_vs, rank,
        ctr, pos_W1, pos_b1, pos_W2, pos_b2, posv);
    k_point_head<<<(NP_ + 255) / 256, 256, 0, stream>>>(
        output_feats, input_map, lin_W1, lin_b1, lin_g, lin_be, lin_W2, lin_b2, o_sem, NP_);
    k_mean<<<(S_ * 32) / 256, 256, 0, stream>>>(output_feats, vidx, pt_start, emb);
    k_ecc<<<1024, 256, 0, stream>>>(emb, W_ecc, ecc);
    k_super<<<1024, 448, 0, stream>>>(ecc, Wq, Wk, Wv,
        (const float*)d_in[13], (const float*)d_in[14], (const float*)d_in[15],
        (const float*)d_in[16], (const float*)d_in[17], (const float*)d_in[18],
        (const float*)d_in[19], (const float*)d_in[20], (const float*)d_in[21],
        (const float*)d_in[22], (const float*)d_in[23], (const float*)d_in[24],
        (const float*)d_in[25], (const float*)d_in[26], (const float*)d_in[27],
        (const float*)d_in[28], (const float*)d_in[29], (const float*)d_in[30],
        (const float*)d_in[31], (const float*)d_in[32], (const float*)d_in[33],
        (const float*)d_in[34], (const float*)d_in[35], (const float*)d_in[36],
        qb, kvb, o_spsem, o_spoff, o_spocc, o_spsize);
    k_attn<<<S_ / 4, 256, 0, stream>>>(e_start, e_list, e_vs, posv, qb, kvb, ecc,
        affs, o_soft, featb);
    k_featd<<<1024, 256, 0, stream>>>(featb,
        (const float*)d_in[37], (const float*)d_in[38], (const float*)d_in[39],
        (const float*)d_in[40], (const float*)d_in[41], (const float*)d_in[42],
        o_spdisc);
}

// Round 4
// 1101.043 us; speedup vs baseline: 1.3626x; 1.0573x over previous
//
#include <hip/hip_runtime.h>

#define NP_ 1500000
#define NV_ 1200000
#define S_  50000
#define E_  1600000
#define SP  50048   // S_ padded to 782*64 (tile granularity)

// ---------------- CSR build ----------------

__global__ void k_zero2(int* a, int* b, int n) {
    int i = blockIdx.x * blockDim.x + threadIdx.x;
    if (i < n) { a[i] = 0; b[i] = 0; }
}

// single atomic pass: rank within segment + counts (counter doubles as histogram)
__global__ __launch_bounds__(256) void k_rank(
    const int* __restrict__ sp, int* __restrict__ pcnt,
    const int* __restrict__ eu, int* __restrict__ ecnt,
    int* __restrict__ rank)
{
    int i = blockIdx.x * 256 + threadIdx.x;
    if (i < NP_) {
        rank[i] = atomicAdd(&pcnt[sp[i]], 1);
    } else if (i < NP_ + E_) {
        rank[i] = atomicAdd(&ecnt[eu[i - NP_]], 1);
    }
}

// exclusive scan over S_ ints; block 0 -> points, block 1 -> edges
__global__ void k_scan2(const int* __restrict__ pcnt, int* __restrict__ pstart,
                        const int* __restrict__ ecnt, int* __restrict__ estart) {
    __shared__ int sums[1024];
    const int* cnt = (blockIdx.x == 0) ? pcnt : ecnt;
    int* start = (blockIdx.x == 0) ? pstart : estart;
    const int n = S_;
    int t = threadIdx.x;
    int chunk = (n + 1023) / 1024;
    int lo = t * chunk;
    int hi = lo + chunk; if (hi > n) hi = n;
    int s = 0;
    for (int i = lo; i < hi; i++) s += cnt[i];
    sums[t] = s;
    __syncthreads();
    for (int off = 1; off < 1024; off <<= 1) {
        int v = (t >= off) ? sums[t - off] : 0;
        __syncthreads();
        sums[t] += v;
        __syncthreads();
    }
    int run = sums[t] - s;  // exclusive prefix
    for (int i = lo; i < hi; i++) { start[i] = run; run += cnt[i]; }
    if (t == 1023) start[n] = run;
}

// atomic-free scatter: points fill vidx; edges fill list/evs + fused pos MLP
__global__ __launch_bounds__(256) void k_scatter(
    const int* __restrict__ sp, const int* __restrict__ imap,
    const int* __restrict__ pstart, int* __restrict__ vidx,
    const int* __restrict__ eu, const int* __restrict__ ev,
    const int* __restrict__ estart,
    int* __restrict__ elist, int* __restrict__ evsarr,
    const int* __restrict__ rank,
    const float* __restrict__ ctr,
    const float* __restrict__ pw1, const float* __restrict__ pb1,
    const float* __restrict__ pw2, const float* __restrict__ pb2,
    float* __restrict__ posv)
{
    int i = blockIdx.x * 256 + threadIdx.x;
    if (i < NP_) {
        vidx[pstart[sp[i]] + rank[i]] = imap[i];
    } else if (i < NP_ + E_) {
        int e = i - NP_;
        int u = eu[e], w = ev[e];
        int r = estart[u] + rank[i];
        elist[r] = e;
        evsarr[r] = w;
        float dx = ctr[u * 3]     - ctr[w * 3];
        float dy = ctr[u * 3 + 1] - ctr[w * 3 + 1];
        float dz = ctr[u * 3 + 2] - ctr[w * 3 + 2];
        float pos = pb2[0];   // uniform -> s_load
        #pragma unroll
        for (int hh = 0; hh < 16; hh++) {
            float aa = pb1[hh] + dx * pw1[hh * 3] + dy * pw1[hh * 3 + 1] + dz * pw1[hh * 3 + 2];
            pos += fmaxf(aa, 0.0f) * pw2[hh];
        }
        posv[r] = pos;
    }
}

// ---------------- weight transpose prep (runs once, ~us) ----------------
// wT layout (floats): [0..2048)   WeccT  [32][64]
//                     [2048 + k*4096) for k=0..7: WqT WkT WvT W1sT W1oT W1cT W1zT W1fT

__global__ void k_prep(const float* __restrict__ Wecc,
                       const float* __restrict__ Wq, const float* __restrict__ Wk,
                       const float* __restrict__ Wv,
                       const float* __restrict__ W1s, const float* __restrict__ W1o,
                       const float* __restrict__ W1c, const float* __restrict__ W1z,
                       const float* __restrict__ W1f, float* __restrict__ wT)
{
    int b = blockIdx.x, t = threadIdx.x;
    if (b == 0) {
        for (int idx = t; idx < 2048; idx += 256) {
            int i = idx >> 6, j = idx & 63;           // i<32 in-dim, j<64 out-dim
            wT[idx] = Wecc[j * 32 + i];
        }
    } else {
        const float* src = b == 1 ? Wq : b == 2 ? Wk : b == 3 ? Wv : b == 4 ? W1s
                         : b == 5 ? W1o : b == 6 ? W1c : b == 7 ? W1z : W1f;
        float* dst = wT + 2048 + (b - 1) * 4096;
        for (int idx = t; idx < 4096; idx += 256) {
            int i = idx >> 6, j = idx & 63;
            dst[idx] = src[j * 64 + i];
        }
    }
}

// ---------------- point semantic head: gather + 32->32 BN ReLU ->20 ----------------

__global__ __launch_bounds__(256, 4) void k_point_head(
    const float* __restrict__ feats, const int* __restrict__ imap,
    const float* __restrict__ W1, const float* __restrict__ b1,
    const float* __restrict__ g, const float* __restrict__ be,
    const float* __restrict__ W2, const float* __restrict__ b2,
    float* __restrict__ out, int n)
{
    int p = blockIdx.x * 256 + threadIdx.x;
    if (p >= n) return;
    const float4* src = (const float4*)(feats + (size_t)imap[p] * 32);
    float x[32];
    #pragma unroll
    for (int i = 0; i < 8; i++) {
        float4 t = src[i];
        x[i * 4] = t.x; x[i * 4 + 1] = t.y; x[i * 4 + 2] = t.z; x[i * 4 + 3] = t.w;
    }
    float o[20];
    #pragma unroll
    for (int c = 0; c < 20; c++) o[c] = b2[c];
    #pragma unroll
    for (int j = 0; j < 32; j++) {
        float a = b1[j];
        #pragma unroll
        for (int i = 0; i < 32; i++) a = fmaf(x[i], W1[j * 32 + i], a);
        a = a * (g[j] * 0.9999500037f) + be[j];
        a = fmaxf(a, 0.0f);
        #pragma unroll
        for (int c = 0; c < 20; c++) o[c] = fmaf(a, W2[c * 32 + j], o[c]);
    }
    float4* dst = (float4*)(out + (size_t)p * 20);
    #pragma unroll
    for (int i = 0; i < 5; i++) {
        float4 o4;
        o4.x = o[i * 4]; o4.y = o[i * 4 + 1]; o4.z = o[i * 4 + 2]; o4.w = o[i * 4 + 3];
        dst[i] = o4;
    }
}

// ---------------- segment mean via CSR (half-wave = 32 dims per superpoint) ----------------

__global__ __launch_bounds__(256) void k_mean(
    const float* __restrict__ feats, const int* __restrict__ vidx,
    const int* __restrict__ start, float* __restrict__ emb)
{
    int t = blockIdx.x * 256 + threadIdx.x;
    int s = t >> 5, d = t & 31;
    if (s >= S_) return;
    int beg = start[s], end = start[s + 1];
    float acc = 0.0f;
    int i = beg;
    for (; i + 4 <= end; i += 4) {
        int p0 = vidx[i], p1 = vidx[i + 1], p2 = vidx[i + 2], p3 = vidx[i + 3];
        float f0 = feats[(size_t)p0 * 32 + d];
        float f1 = feats[(size_t)p1 * 32 + d];
        float f2 = feats[(size_t)p2 * 32 + d];
        float f3 = feats[(size_t)p3 * 32 + d];
        acc += f0 + f1 + f2 + f3;
    }
    for (; i < end; i++) acc += feats[(size_t)vidx[i] * 32 + d];
    float c = (float)(end - beg);
    emb[(size_t)s * 32 + d] = acc / fmaxf(c, 1.0f);
}

// ---------------- emb -> embT (LDS tile transpose; pad rows = 0) ----------------

__global__ __launch_bounds__(256) void k_trans_emb(
    const float* __restrict__ emb, float* __restrict__ embT)
{
    __shared__ float L[64][33];
    int base = blockIdx.x * 64;
    int t = threadIdx.x;
    for (int idx = t; idx < 2048; idx += 256) {
        int r = idx >> 5, c = idx & 31;
        int s = base + r;
        L[r][c] = s < S_ ? emb[(size_t)s * 32 + c] : 0.0f;
    }
    __syncthreads();
    for (int idx = t; idx < 2048; idx += 256) {
        int i = idx >> 6, rr = idx & 63;
        embT[(size_t)i * SP + base + rr] = L[rr][i];
    }
}

// ---------------- ecc: lane=row tile, coalesced embT stream, scalar WeccT ----------------
// writes eccT [64][SP] (pad rows come out 0 since embT pad = 0)

__global__ __launch_bounds__(512) void k_ecc_t(
    const float* __restrict__ embT, const float* __restrict__ wT, float* __restrict__ eccT)
{
    int wid = threadIdx.x >> 6, lane = threadIdx.x & 63;
    int T = blockIdx.x * 8 + wid;
    if (T >= 782) return;
    int r = T * 64 + lane;
    float acc[64];
    #pragma unroll
    for (int j = 0; j < 64; j++) acc[j] = 0.0f;
    #pragma unroll 2
    for (int i = 0; i < 32; i++) {
        float xi = embT[(size_t)i * SP + r];
        const float* w = wT + i * 64;     // uniform -> s_load stream
        #pragma unroll
        for (int j = 0; j < 64; j++) acc[j] = fmaf(xi, w[j], acc[j]);
    }
    #pragma unroll
    for (int j = 0; j < 64; j++) eccT[(size_t)j * SP + r] = acc[j];
}

// ---------------- fused superpoint matmuls: lane=row tiles, role = blockIdx.y ----------------
// roles: 0=q 1=k 2=v 3=ssem 4=soff 5=socc 6=ssize
// x streamed coalesced from eccT; W1^T streamed via scalar path (16 KB, sL1-hot);
// per-lane acc[64] holds the full output/hidden row -> layer2 entirely lane-local.

__global__ __launch_bounds__(512) void k_super_t(
    const float* __restrict__ eccT, const float* __restrict__ wT,
    const float* __restrict__ b1s, const float* __restrict__ gs, const float* __restrict__ bes,
    const float* __restrict__ W2s, const float* __restrict__ b2s,
    const float* __restrict__ b1o, const float* __restrict__ go, const float* __restrict__ beo,
    const float* __restrict__ W2o, const float* __restrict__ b2o,
    const float* __restrict__ b1c, const float* __restrict__ gc, const float* __restrict__ bec,
    const float* __restrict__ W2c, const float* __restrict__ b2c,
    const float* __restrict__ b1z, const float* __restrict__ gz, const float* __restrict__ bez,
    const float* __restrict__ W2z, const float* __restrict__ b2z,
    float* __restrict__ q, float* __restrict__ kv,
    float* __restrict__ osem, float* __restrict__ ooff,
    float* __restrict__ oocc, float* __restrict__ osiz)
{
    int role = blockIdx.y;
    int wid = threadIdx.x >> 6, lane = threadIdx.x & 63;
    const float* WT = wT + 2048 + role * 4096;

    for (int T = blockIdx.x * 8 + wid; T < 782; T += 392) {
        int r = T * 64 + lane;
        bool ok = r < S_;
        float acc[64];
        #pragma unroll
        for (int j = 0; j < 64; j++) acc[j] = 0.0f;
        #pragma unroll 2
        for (int i = 0; i < 64; i++) {
            float xi = eccT[(size_t)i * SP + r];   // coalesced 256B wave load
            const float* w = WT + i * 64;          // uniform -> s_load stream
            #pragma unroll
            for (int j = 0; j < 64; j++) acc[j] = fmaf(xi, w[j], acc[j]);
        }
        if (role < 3) {
            float* outp; int stride;
            if (role == 0)      { outp = q;       stride = 64;  }
            else if (role == 1) { outp = kv;      stride = 128; }
            else                { outp = kv + 64; stride = 128; }
            if (ok) {
                #pragma unroll
                for (int j0 = 0; j0 < 64; j0 += 4) {
                    float4 o4;
                    o4.x = acc[j0]; o4.y = acc[j0 + 1]; o4.z = acc[j0 + 2]; o4.w = acc[j0 + 3];
                    *(float4*)(outp + (size_t)r * stride + j0) = o4;
                }
            }
        } else if (role == 3) {
            #pragma unroll
            for (int j = 0; j < 64; j++) {
                float a = acc[j] + b1s[j];
                a = a * (gs[j] * 0.9999500037f) + bes[j];
                acc[j] = fmaxf(a, 0.0f);
            }
            float o[20];
            #pragma unroll
            for (int c = 0; c < 20; c++) {
                float a = b2s[c];
                #pragma unroll
                for (int j = 0; j < 64; j++) a = fmaf(acc[j], W2s[c * 64 + j], a);
                o[c] = a;
            }
            if (ok) {
                #pragma unroll
                for (int c0 = 0; c0 < 20; c0 += 4) {
                    float4 o4;
                    o4.x = o[c0]; o4.y = o[c0 + 1]; o4.z = o[c0 + 2]; o4.w = o[c0 + 3];
                    *(float4*)(osem + (size_t)r * 20 + c0) = o4;
                }
            }
        } else if (role == 4) {
            #pragma unroll
            for (int j = 0; j < 64; j++) {
                float a = acc[j] + b1o[j];
                a = a * (go[j] * 0.9999500037f) + beo[j];
                acc[j] = fmaxf(a, 0.0f);
            }
            float o0 = b2o[0], o1 = b2o[1], o2 = b2o[2];
            #pragma unroll
            for (int j = 0; j < 64; j++) {
                o0 = fmaf(acc[j], W2o[j], o0);
                o1 = fmaf(acc[j], W2o[64 + j], o1);
                o2 = fmaf(acc[j], W2o[128 + j], o2);
            }
            if (ok) {
                ooff[(size_t)r * 3]     = o0;
                ooff[(size_t)r * 3 + 1] = o1;
                ooff[(size_t)r * 3 + 2] = o2;
            }
        } else {
            const float* b1p = (role == 5) ? b1c : b1z;
            const float* gp  = (role == 5) ? gc  : gz;
            const float* bep = (role == 5) ? bec : bez;
            const float* W2p = (role == 5) ? W2c : W2z;
            const float* b2p = (role == 5) ? b2c : b2z;
            float* outp = (role == 5) ? oocc : osiz;
            float o0 = b2p[0];
            #pragma unroll
            for (int j = 0; j < 64; j++) {
                float a = acc[j] + b1p[j];
                a = a * (gp[j] * 0.9999500037f) + bep[j];
                o0 = fmaf(fmaxf(a, 0.0f), W2p[j], o0);
            }
            if (ok) outp[r] = o0;
        }
    }
}

// ---------------- disc head (featb -> 7): lane=row tile ----------------

__global__ __launch_bounds__(512) void k_featd_t(
    const float* __restrict__ featb, const float* __restrict__ wT,
    const float* __restrict__ b1, const float* __restrict__ g, const float* __restrict__ be,
    const float* __restrict__ W2, const float* __restrict__ b2,
    float* __restrict__ out)
{
    int wid = threadIdx.x >> 6, lane = threadIdx.x & 63;
    int T = blockIdx.x * 8 + wid;
    if (T >= 782) return;
    int r = T * 64 + lane;
    bool ok = r < S_;
    const float* xrow = featb + (size_t)(ok ? r : 0) * 64;
    const float* WT = wT + 2048 + 7 * 4096;
    float acc[64];
    #pragma unroll
    for (int j = 0; j < 64; j++) acc[j] = 0.0f;
    #pragma unroll 2
    for (int i = 0; i < 64; i++) {
        float xi = xrow[i];                       // per-lane row, L2-resident
        const float* w = WT + i * 64;             // uniform -> s_load stream
        #pragma unroll
        for (int j = 0; j < 64; j++) acc[j] = fmaf(xi, w[j], acc[j]);
    }
    #pragma unroll
    for (int j = 0; j < 64; j++) {
        float a = acc[j] + b1[j];
        a = a * (g[j] * 0.9999500037f) + be[j];
        acc[j] = fmaxf(a, 0.0f);
    }
    float o[7];
    #pragma unroll
    for (int c = 0; c < 7; c++) {
        float a = b2[c];
        #pragma unroll
        for (int j = 0; j < 64; j++) a = fmaf(acc[j], W2[c * 64 + j], a);
        o[c] = a;
    }
    if (ok) {
        #pragma unroll
        for (int c = 0; c < 7; c++) out[(size_t)r * 7 + c] = o[c];
    }
}

// ---------------- fused attention: single gather sweep, online softmax ----------------

__global__ __launch_bounds__(256) void k_attn(
    const int* __restrict__ start, const int* __restrict__ list,
    const int* __restrict__ evs, const float* __restrict__ posv,
    const float* __restrict__ q, const float* __restrict__ kv,
    const float* __restrict__ eccT,
    float* __restrict__ affs, float* __restrict__ soft, float* __restrict__ featb)
{
    int t = blockIdx.x * 256 + threadIdx.x;
    int s0 = t >> 6, lane = t & 63;
    if (s0 >= S_) return;
    int s = __builtin_amdgcn_readfirstlane(s0);  // uniform: evs/posv/affs scalarize
    int beg = start[s], end = start[s + 1];
    float qv = q[(size_t)s * 64 + lane];

    float m = -3.0e38f, tot = 0.0f, res = 0.0f;
    int r = beg;
    for (; r + 8 <= end; r += 8) {
        int e[8];
        #pragma unroll
        for (int u = 0; u < 8; u++) e[u] = evs[r + u];
        float kk[8], vv[8];
        #pragma unroll
        for (int u = 0; u < 8; u++) {
            const float* row = kv + (size_t)e[u] * 128;
            kk[u] = row[lane];
            vv[u] = row[64 + lane];
        }
        float p[8];
        #pragma unroll
        for (int u = 0; u < 8; u++) p[u] = qv * kk[u];
        #pragma unroll
        for (int o = 32; o; o >>= 1) {
            #pragma unroll
            for (int u = 0; u < 8; u++) p[u] += __shfl_xor(p[u], o, 64);
        }
        float a[8];
        float cm = -3.0e38f;
        #pragma unroll
        for (int u = 0; u < 8; u++) { a[u] = p[u] * 0.125f * posv[r + u]; cm = fmaxf(cm, a[u]); }
        float mn = fmaxf(m, cm);
        float scale = __expf(m - mn);
        res *= scale; tot *= scale; m = mn;
        #pragma unroll
        for (int u = 0; u < 8; u++) {
            float w = __expf(a[u] - m);
            tot += w;
            res = fmaf(w, vv[u], res);
        }
        float av = a[0];
        #pragma unroll
        for (int u = 1; u < 8; u++) av = (lane == u) ? a[u] : av;
        if (lane < 8) affs[r + lane] = av;
    }
    for (; r < end; r++) {
        const float* row = kv + (size_t)evs[r] * 128;
        float kk = row[lane], vv = row[64 + lane];
        float p = qv * kk;
        #pragma unroll
        for (int o = 32; o; o >>= 1) p += __shfl_xor(p, o, 64);
        float a = p * 0.125f * posv[r];
        float mn = fmaxf(m, a);
        float scale = __expf(m - mn);
        res *= scale; tot *= scale; m = mn;
        float w = __expf(a - m);
        tot += w;
        res = fmaf(w, vv, res);
        if (lane == 0) affs[r] = a;
    }
    float inv = tot > 0.0f ? 1.0f / tot : 0.0f;

    // soft scatter from coalesced affs re-read
    for (int i = beg + lane; i < end; i += 64) soft[list[i]] = __expf(affs[i] - m) * inv;

    featb[(size_t)s * 64 + lane] = eccT[(size_t)lane * SP + s] + res * inv;
}

// ---------------- launch ----------------

extern "C" void kernel_launch(void* const* d_in, const int* in_sizes, int n_in,
                              void* d_out, int out_size, void* d_ws, size_t ws_size,
                              hipStream_t stream) {
    const float* output_feats = (const float*)d_in[0];
    const int*   input_map    = (const int*)d_in[1];
    const int*   superpoint   = (const int*)d_in[2];
    const float* ctr          = (const float*)d_in[3];
    const int*   edge_u       = (const int*)d_in[4];
    const int*   edge_v       = (const int*)d_in[5];
    const float* W_ecc        = (const float*)d_in[6];
    const float* lin_W1 = (const float*)d_in[7];
    const float* lin_b1 = (const float*)d_in[8];
    const float* lin_g  = (const float*)d_in[9];
    const float* lin_be = (const float*)d_in[10];
    const float* lin_W2 = (const float*)d_in[11];
    const float* lin_b2 = (const float*)d_in[12];
    const float* pos_W1 = (const float*)d_in[43];
    const float* pos_b1 = (const float*)d_in[44];
    const float* pos_W2 = (const float*)d_in[45];
    const float* pos_b2 = (const float*)d_in[46];
    const float* Wq     = (const float*)d_in[47];
    const float* Wk     = (const float*)d_in[48];
    const float* Wv     = (const float*)d_in[49];

    float* out = (float*)d_out;
    float* o_sem    = out;                    // [NP,20]
    float* o_spsem  = out + 30000000;         // [S,20]
    float* o_spoff  = out + 31000000;         // [S,3]
    float* o_spocc  = out + 31150000;         // [S]
    float* o_spsize = out + 31200000;         // [S]
    float* o_soft   = out + 31250000;         // [E]
    float* o_spdisc = out + 32850000;         // [S,7]

    // workspace layout
    char* base = (char*)d_ws;
    size_t off = 0;
    auto alloc = [&](size_t bytes) -> char* {
        char* p = base + off;
        off = (off + bytes + 255) & ~(size_t)255;
        return p;
    };
    int*   pt_cnt   = (int*)alloc(S_ * 4);
    int*   pt_start = (int*)alloc((S_ + 1) * 4);
    int*   e_cnt    = (int*)alloc(S_ * 4);
    int*   e_start  = (int*)alloc((S_ + 1) * 4);
    int*   vidx     = (int*)alloc((size_t)NP_ * 4);
    int*   e_list   = (int*)alloc((size_t)E_ * 4);
    int*   e_vs     = (int*)alloc((size_t)E_ * 4);
    float* affs     = (float*)alloc((size_t)E_ * 4);
    float* posv     = (float*)alloc((size_t)E_ * 4);
    float* emb      = (float*)alloc((size_t)S_ * 32 * 4);   // row-major (k_mean out)
    float* embT     = (float*)alloc((size_t)32 * SP * 4);   // [32][SP]
    float* eccT     = (float*)alloc((size_t)64 * SP * 4);   // [64][SP]
    float* qb       = (float*)alloc((size_t)S_ * 64 * 4);
    float* kvb      = (float*)alloc((size_t)S_ * 128 * 4);
    float* wT       = (float*)alloc((size_t)34816 * 4);     // transposed weights
    float* featb    = qb;            // overlay: wave s reads q-row s before writing featb-row s
    int*   rank     = (int*)emb;     // overlay: rank dead before k_mean/k_trans_emb run
                                     // (NP_+E_)*4 = 12.4 MB < emb(6.4) + embT(6.4)

    const int NTOT = NP_ + E_;

    k_prep<<<9, 256, 0, stream>>>(W_ecc, Wq, Wk, Wv,
        (const float*)d_in[13], (const float*)d_in[19],
        (const float*)d_in[25], (const float*)d_in[31],
        (const float*)d_in[37], wT);
    k_zero2<<<(S_ + 255) / 256, 256, 0, stream>>>(pt_cnt, e_cnt, S_);
    k_rank<<<(NTOT + 255) / 256, 256, 0, stream>>>(superpoint, pt_cnt, edge_u, e_cnt, rank);
    k_scan2<<<2, 1024, 0, stream>>>(pt_cnt, pt_start, e_cnt, e_start);
    k_scatter<<<(NTOT + 255) / 256, 256, 0, stream>>>(
        superpoint, input_map, pt_start, vidx,
        edge_u, edge_v, e_start, e_list, e_vs, rank,
        ctr, pos_W1, pos_b1, pos_W2, pos_b2, posv);
    k_point_head<<<(NP_ + 255) / 256, 256, 0, stream>>>(
        output_feats, input_map, lin_W1, lin_b1, lin_g, lin_be, lin_W2, lin_b2, o_sem, NP_);
    k_mean<<<(S_ * 32) / 256, 256, 0, stream>>>(output_feats, vidx, pt_start, emb);
    k_trans_emb<<<782, 256, 0, stream>>>(emb, embT);
    k_ecc_t<<<98, 512, 0, stream>>>(embT, wT, eccT);
    k_super_t<<<dim3(49, 7), 512, 0, stream>>>(eccT, wT,
        (const float*)d_in[14], (const float*)d_in[15], (const float*)d_in[16],
        (const float*)d_in[17], (const float*)d_in[18],
        (const float*)d_in[20], (const float*)d_in[21], (const float*)d_in[22],
        (const float*)d_in[23], (const float*)d_in[24],
        (const float*)d_in[26], (const float*)d_in[27], (const float*)d_in[28],
        (const float*)d_in[29], (const float*)d_in[30],
        (const float*)d_in[32], (const float*)d_in[33], (const float*)d_in[34],
        (const float*)d_in[35], (const float*)d_in[36],
        qb, kvb, o_spsem, o_spoff, o_spocc, o_spsize);
    k_attn<<<S_ / 4, 256, 0, stream>>>(e_start, e_list, e_vs, posv, qb, kvb, eccT,
        affs, o_soft, featb);
    k_featd_t<<<98, 512, 0, stream>>>(featb, wT,
        (const float*)d_in[38], (const float*)d_in[39], (const float*)d_in[40],
        (const float*)d_in[41], (const float*)d_in[42],
        o_spdisc);
}